// Round 14
// baseline (8647.655 us; speedup 1.0000x reference)
//
#include <hip/hip_runtime.h>
#include <hip/hip_bf16.h>
#include <hip/hip_fp16.h>

// Problem constants
#define NB 256   // batch
#define NH 512   // hidden
#define NL 3     // lstm layers
#define NT 200   // time steps
#define NV 100   // vocab
#define NVP 112  // vocab padded to 7*16
#define NG 2048  // 4*NH gate rows per layer (permuted r = hu*4+g)
#define NK 1024  // 2*NH (proj2 K)
#define NS (NT * NL)  // 600 chain cells; s = 3t+l; input(s) = output(s-1)

using f16x8 = __attribute__((ext_vector_type(8))) _Float16;
using f32x4 = __attribute__((ext_vector_type(4))) float;
using u32x4 = __attribute__((ext_vector_type(4))) unsigned int;

__device__ __forceinline__ float sigf(float x) { return 1.f / (1.f + __expf(-x)); }
__device__ __forceinline__ float tanhf_(float x) { return 2.f / (1.f + __expf(-2.f * x)) - 1.f; }

// ---------------- MFMA layout probe ----------------
__global__ void k_probe(int* __restrict__ rowmap, int* __restrict__ colmap) {
  const int lane = threadIdx.x & 63;
  f16x8 a, b;
  const _Float16 idv = (_Float16)(float)(lane & 15);
  const _Float16 inv = (_Float16)(1.f / 32.f);
#pragma unroll
  for (int j = 0; j < 8; ++j) { a[j] = idv; b[j] = inv; }
  f32x4 d = {0.f, 0.f, 0.f, 0.f};
  d = __builtin_amdgcn_mfma_f32_16x16x32_f16(a, b, d, 0, 0, 0);
#pragma unroll
  for (int r = 0; r < 4; ++r) rowmap[lane * 4 + r] = (int)(d[r] + 0.5f);
#pragma unroll
  for (int j = 0; j < 8; ++j) { a[j] = inv; b[j] = idv; }
  f32x4 e = {0.f, 0.f, 0.f, 0.f};
  e = __builtin_amdgcn_mfma_f32_16x16x32_f16(a, b, e, 0, 0, 0);
#pragma unroll
  for (int r = 0; r < 4; ++r) colmap[lane * 4 + r] = (int)(e[r] + 0.5f);
}

// ---------------- prep: split + permute recurrent weights to fp16 ----------------
__global__ void k_prep_w(const float* __restrict__ w_ih, const float* __restrict__ w_hh,
                         const float* __restrict__ b_ih, const float* __restrict__ b_hh,
                         _Float16* __restrict__ Wih, _Float16* __restrict__ Whh,
                         float* __restrict__ bias) {
  const int stride = gridDim.x * blockDim.x;
  const int tid0 = blockIdx.x * blockDim.x + threadIdx.x;
  for (int idx = tid0; idx < NL * NG * NH; idx += stride) {
    const int k = idx & (NH - 1);
    const int r = (idx >> 9) & (NG - 1);
    const int l = idx >> 20;
    const int hu = r >> 2, g = r & 3;
    const size_t soff = ((size_t)(l * NG + g * NH + hu)) * NH + k;
    Wih[idx] = (_Float16)w_ih[soff];
    Whh[idx] = (_Float16)w_hh[soff];
  }
  for (int idx = tid0; idx < NL * NG; idx += stride) {
    const int r = idx & (NG - 1);
    const int l = idx >> 11;
    const int hu = r >> 2, g = r & 3;
    const int srow = l * NG + g * NH + hu;
    bias[idx] = b_ih[srow] + b_hh[srow];
  }
}

// ---------------- prep: x0, projection weights, flag reset ----------------
__global__ void k_prep_misc(const float* __restrict__ embed, const int* __restrict__ start_idx,
                            const float* __restrict__ w1, const float* __restrict__ b1,
                            const float* __restrict__ w2, const float* __restrict__ b2,
                            _Float16* __restrict__ x0, _Float16* __restrict__ pw1, float* __restrict__ pb1,
                            _Float16* __restrict__ pw2, float* __restrict__ pb2, int* __restrict__ flags) {
  const int stride = gridDim.x * blockDim.x;
  const int tid0 = blockIdx.x * blockDim.x + threadIdx.x;
  for (int i = tid0; i < 256 * 16; i += stride) flags[i] = 0;
  const int st = start_idx[0];
  for (int i = tid0; i < NB * NH; i += stride)
    x0[i] = (_Float16)embed[(size_t)st * NH + (i & (NH - 1))];
  for (int i = tid0; i < 2 * NH * NH; i += stride)
    pw1[i] = (_Float16)w1[i];
  for (int i = tid0; i < NVP * NK; i += stride) {
    const int r = i >> 10;
    pw2[i] = (_Float16)((r < NV) ? w2[i] : 0.f);
  }
  for (int i = tid0; i < 2 * NH; i += stride) pb1[i] = b1[i];
  for (int i = tid0; i < NVP; i += stride) pb2[i] = (i < NV) ? b2[i] : 0.f;
}

// ---------------- visual GEMV ----------------
__global__ void k_gemv512(const float* __restrict__ x, const float* __restrict__ w,
                          const float* __restrict__ bias, float* __restrict__ out) {
  const int b = blockIdx.x;
  __shared__ float xs[NH];
  for (int i = threadIdx.x; i < NH; i += 256) xs[i] = x[(size_t)b * NH + i];
  __syncthreads();
  const int wave = threadIdx.x >> 6, lane = threadIdx.x & 63;
  for (int j = wave; j < NH; j += 4) {
    const float* wr = w + (size_t)j * NH;
    float s = 0.f;
#pragma unroll
    for (int i = 0; i < 8; ++i) s += wr[lane + i * 64] * xs[lane + i * 64];
#pragma unroll
    for (int o = 32; o > 0; o >>= 1) s += __shfl_down(s, o);
    if (lane == 0) out[(size_t)b * NH + j] = s + bias[j];
  }
}

// second visual GEMV -> h0 (fp16)
__global__ void k_gemv2_h0(const float* __restrict__ feat1, const float* __restrict__ w,
                           const float* __restrict__ bias, _Float16* __restrict__ h0b) {
  const int b = blockIdx.x;
  __shared__ float xs[NH];
  for (int i = threadIdx.x; i < NH; i += 256) xs[i] = feat1[(size_t)b * NH + i];
  __syncthreads();
  const int wave = threadIdx.x >> 6, lane = threadIdx.x & 63;
  for (int j = wave; j < NH; j += 4) {
    const float* wr = w + (size_t)j * NH;
    float s = 0.f;
#pragma unroll
    for (int i = 0; i < 8; ++i) s += wr[lane + i * 64] * xs[lane + i * 64];
#pragma unroll
    for (int o = 32; o > 0; o >>= 1) s += __shfl_down(s, o);
    if (lane == 0) h0b[(size_t)b * NH + j] = (_Float16)(s + bias[j]);
  }
}

// ---------------- persistent LSTM chain: 16 groups x 16 blocks ----------------
// Block = (gm = bid>>4: 16-row batch slice, jj = bid&15: 32 hidden units = 128 permuted
// gate rows). XCD (bid%8) hosts 2 jj-slices -> W L2-resident (1.6MB/XCD).
// 8 waves = 8 gate-16-slices, each K=512 as two 8-MFMA chains. Per stage s:
//   phase A: LOAD_AREG (LDS->reg) + x-GEMM -> gl
//   cell:    gl + pend[l] + bias -> hout
//   phase B: wave0 publish (1KB wide volatile); all waves h-GEMM for s+2 (areg + streamed
//            Whh; hides drain); wave0 vmcnt(0)+flag; poll 16 flags; STAGE_A(s+1) 16KB.
__global__ __launch_bounds__(512, 2) void k_lstm(const _Float16* __restrict__ Wih,
                                                 const _Float16* __restrict__ Whh,
                                                 const float* __restrict__ bias,
                                                 _Float16* hx, const _Float16* __restrict__ h0b,
                                                 const _Float16* __restrict__ x0,
                                                 _Float16* __restrict__ outs,
                                                 const int* __restrict__ rowmap,
                                                 const int* __restrict__ colmap,
                                                 int* flags) {
  const int tid = threadIdx.x;
  const int lane = tid & 63;
  const int wave = tid >> 6;       // 0..7 = gate 16-slice
  const int bid = blockIdx.x;
  const int jj = bid & 15;         // hidden-unit slice (32 hu)
  const int gm = bid >> 4;         // batch group (16 rows)
  const int gbase = gm * 16;
  const int lr = lane & 15;
  const int lh = lane >> 4;
  const int nb0 = jj * 128 + wave * 16;  // permuted gate-row base
  __shared__ _Float16 Als[16][512];      // XOR-swizzled: chunk c at (c ^ (row&7))
  __shared__ float gl[16][132];
  __shared__ float pend[3][16][132];
  __shared__ _Float16 hout[16][32];

  int rm[4], cm[4];
#pragma unroll
  for (int r = 0; r < 4; ++r) {
    rm[r] = rowmap[lane * 4 + r];
    cm[r] = colmap[lane * 4 + r];
  }
  const int row_ = tid >> 5;  // cell batch row 0..15
  const int huL = tid & 31;   // local hidden unit 0..31
  float creg[NL] = {0.f, 0.f, 0.f};
  float bsv[NL][4];
#pragma unroll
  for (int l = 0; l < NL; ++l)
#pragma unroll
    for (int g = 0; g < 4; ++g) bsv[l][g] = bias[l * NG + (jj * 32 + huL) * 4 + g];

  f16x8 wx[16], areg[16];

#define PREFETCH(LX)                                                              \
  do {                                                                            \
    const _Float16* wbx = Wih + ((size_t)((LX) * NG + nb0 + lr)) * NH + lh * 8;   \
    _Pragma("unroll") for (int k_ = 0; k_ < 16; ++k_)                             \
        wx[k_] = *(const f16x8*)(wbx + k_ * 32);                                  \
  } while (0)

#define LOAD_AREG()                                                               \
  do {                                                                            \
    _Pragma("unroll") for (int kk = 0; kk < 16; ++kk)                             \
      areg[kk] = *(const f16x8*)&Als[lr][(((kk) * 4 + lh) ^ (lr & 7)) * 8];       \
  } while (0)

#define STAGE_A(SRC, VOLQ)                                                        \
  do {                                                                            \
    _Pragma("unroll") for (int c = 0; c < 2; ++c) {                               \
      const int i_ = tid + c * 512;                                               \
      const int rr = i_ >> 6, cc = i_ & 63;                                       \
      u32x4 v_ = *(const VOLQ u32x4*)((SRC) + (size_t)(gm * 16 + rr) * NH + cc * 8); \
      *(u32x4*)&Als[rr][(cc ^ (rr & 7)) * 8] = v_;                                \
    }                                                                             \
  } while (0)

  // ---- prologue: pend[lp] = h0 @ Whh[lp]^T for the t=0 cells ----
  STAGE_A(h0b, );
  __syncthreads();
  LOAD_AREG();
#pragma unroll 1
  for (int lp = 0; lp < 3; ++lp) {
    const _Float16* wbh = Whh + ((size_t)(lp * NG + nb0 + lr)) * NH + lh * 8;
    f32x4 aA = {0.f, 0.f, 0.f, 0.f}, aB = {0.f, 0.f, 0.f, 0.f};
#pragma unroll
    for (int kk = 0; kk < 8; ++kk) {
      aA = __builtin_amdgcn_mfma_f32_16x16x32_f16(areg[kk], *(const f16x8*)(wbh + kk * 32), aA, 0, 0, 0);
      aB = __builtin_amdgcn_mfma_f32_16x16x32_f16(areg[8 + kk], *(const f16x8*)(wbh + (8 + kk) * 32), aB, 0, 0, 0);
    }
#pragma unroll
    for (int r = 0; r < 4; ++r)
      pend[lp][rm[r]][wave * 16 + cm[r]] = aA[r] + aB[r];
  }
  PREFETCH(0);
  __syncthreads();
  STAGE_A(x0, );  // A for s=0
  __syncthreads();

  // ---- main chain ----
#pragma unroll 1
  for (int t = 0; t < NT; ++t) {
#pragma unroll
    for (int l = 0; l < NL; ++l) {
      const int s = t * 3 + l;
      // phase A: x-GEMM
      LOAD_AREG();
      {
        f32x4 aA = {0.f, 0.f, 0.f, 0.f}, aB = {0.f, 0.f, 0.f, 0.f};
#pragma unroll
        for (int kk = 0; kk < 8; ++kk) {
          aA = __builtin_amdgcn_mfma_f32_16x16x32_f16(areg[kk], wx[kk], aA, 0, 0, 0);
          aB = __builtin_amdgcn_mfma_f32_16x16x32_f16(areg[8 + kk], wx[8 + kk], aB, 0, 0, 0);
        }
#pragma unroll
        for (int r = 0; r < 4; ++r)
          gl[rm[r]][wave * 16 + cm[r]] = aA[r] + aB[r];
      }
      __syncthreads();
      // cell update
      {
        const f32x4 gx = *(const f32x4*)&gl[row_][huL * 4];
        const f32x4 gh = *(const f32x4*)&pend[l][row_][huL * 4];
        const float gi = gx[0] + gh[0] + bsv[l][0];
        const float gf = gx[1] + gh[1] + bsv[l][1];
        const float gg = gx[2] + gh[2] + bsv[l][2];
        const float go = gx[3] + gh[3] + bsv[l][3];
        const float cn = sigf(gf) * creg[l] + sigf(gi) * tanhf_(gg);
        const float hn = sigf(go) * tanhf_(cn);
        creg[l] = cn;
        hout[row_][huL] = (_Float16)hn;
      }
      __syncthreads();
      // phase B: publish + h-GEMM for s+2 (register A, streamed Whh) + flag + poll + stage
      if (wave == 0) {
        const int row = lane >> 2, q = lane & 3;
        _Float16* dst = hx + (size_t)(s & 1) * NB * NH + (size_t)(gm * 16 + row) * NH + jj * 32 + q * 8;
        u32x4 v = *(const u32x4*)&hout[row][q * 8];
        *(volatile u32x4*)dst = v;
      }
      if (s >= 1 && s <= NS - 3) {
        const int l2 = (l + 2) % 3;
        const _Float16* wbh = Whh + ((size_t)(l2 * NG + nb0 + lr)) * NH + lh * 8;
        f32x4 aA = {0.f, 0.f, 0.f, 0.f}, aB = {0.f, 0.f, 0.f, 0.f};
#pragma unroll
        for (int kk = 0; kk < 8; ++kk) {
          aA = __builtin_amdgcn_mfma_f32_16x16x32_f16(areg[kk], *(const f16x8*)(wbh + kk * 32), aA, 0, 0, 0);
          aB = __builtin_amdgcn_mfma_f32_16x16x32_f16(areg[8 + kk], *(const f16x8*)(wbh + (8 + kk) * 32), aB, 0, 0, 0);
        }
#pragma unroll
        for (int r = 0; r < 4; ++r)
          pend[l2][rm[r]][wave * 16 + cm[r]] = aA[r] + aB[r];
      }
      if (wave == 0) {
        asm volatile("s_waitcnt vmcnt(0)" ::: "memory");
        if (lane == 0) *(volatile int*)&flags[(gbase + jj) * 16] = s + 1;
      }
      if (wave == 1 && l == 2) {
        const int row = lane >> 2, q = lane & 3;
        _Float16* dst = outs + ((size_t)t * NB + gm * 16 + row) * NH + jj * 32 + q * 8;
        *(u32x4*)dst = *(const u32x4*)&hout[row][q * 8];
      }
      if (s < NS - 1) {
        PREFETCH((l + 1) % 3);  // Wih for stage s+1
        if (lane < 16) {
          const volatile int* fp = (const volatile int*)&flags[(gbase + lane) * 16];
          while (*fp < s + 1) __builtin_amdgcn_s_sleep(1);
        }
        STAGE_A(hx + (size_t)(s & 1) * NB * NH, volatile);
        __syncthreads();
      }
    }
  }
#undef STAGE_A
#undef LOAD_AREG
#undef PREFETCH
}

// ---------------- projection head (fused, r12-proven): gelu(res@W1^T+b1)@W2^T+b2 -> out ----------------
__global__ __launch_bounds__(256) void k_proj(const _Float16* __restrict__ outs, const _Float16* __restrict__ pw1,
                                              const float* __restrict__ pb1, const _Float16* __restrict__ pw2,
                                              const float* __restrict__ pb2,
                                              const int* __restrict__ rowmap, const int* __restrict__ colmap,
                                              float* __restrict__ out) {
  const int tid = threadIdx.x;
  const int lane = tid & 63;
  const int wave = tid >> 6;
  const int lr = lane & 15;
  const int lh = lane >> 4;
  const int mbase = blockIdx.x * 16;
  __shared__ _Float16 hm[16][NK + 8];
  int rm[4], cm[4];
#pragma unroll
  for (int r = 0; r < 4; ++r) {
    rm[r] = rowmap[lane * 4 + r];
    cm[r] = colmap[lane * 4 + r];
  }
  const int mrow = mbase + lr;
  const _Float16* ap = outs + ((size_t)(mrow % NT) * NB + (mrow / NT)) * NH + lh * 8;
  for (int nf = 0; nf < 16; ++nf) {
    const int n0 = wave * 256 + nf * 16;
    f32x4 acc = {0.f, 0.f, 0.f, 0.f};
    const _Float16* bp = pw1 + (size_t)(n0 + lr) * NH + lh * 8;
#pragma unroll 4
    for (int kk = 0; kk < 16; ++kk) {
      f16x8 a = *(const f16x8*)(ap + kk * 32);
      f16x8 b = *(const f16x8*)(bp + kk * 32);
      acc = __builtin_amdgcn_mfma_f32_16x16x32_f16(a, b, acc, 0, 0, 0);
    }
#pragma unroll
    for (int r = 0; r < 4; ++r) {
      const float v = acc[r] + pb1[n0 + cm[r]];
      const float gv = 0.5f * v * (1.f + erff(v * 0.70710678118654752f));
      hm[rm[r]][n0 + cm[r]] = (_Float16)gv;
    }
  }
  __syncthreads();
  for (int nf = wave; nf < 7; nf += 4) {
    const int n0 = nf * 16;
    f32x4 acc = {0.f, 0.f, 0.f, 0.f};
    const _Float16* bp = pw2 + (size_t)(n0 + lr) * NK + lh * 8;
#pragma unroll 4
    for (int kk = 0; kk < 32; ++kk) {
      f16x8 a = *(const f16x8*)(&hm[lr][kk * 32 + lh * 8]);
      f16x8 b = *(const f16x8*)(bp + kk * 32);
      acc = __builtin_amdgcn_mfma_f32_16x16x32_f16(a, b, acc, 0, 0, 0);
    }
#pragma unroll
    for (int r = 0; r < 4; ++r) {
      const int v = n0 + cm[r];
      if (v < NV) {
        const int m = mbase + rm[r];
        out[((size_t)(m / NT) * NV + v) * NT + (m % NT)] = acc[r] + pb2[v];
      }
    }
  }
}

extern "C" void kernel_launch(void* const* d_in, const int* in_sizes, int n_in,
                              void* d_out, int out_size, void* d_ws, size_t ws_size,
                              hipStream_t stream) {
  const float* feat = (const float*)d_in[0];
  const float* visual_w = (const float*)d_in[1];
  const float* visual_b = (const float*)d_in[2];
  const float* embed = (const float*)d_in[3];
  const float* w_ih = (const float*)d_in[4];
  const float* w_hh = (const float*)d_in[5];
  const float* b_ih = (const float*)d_in[6];
  const float* b_hh = (const float*)d_in[7];
  const float* proj_w1 = (const float*)d_in[8];
  const float* proj_b1 = (const float*)d_in[9];
  const float* proj_w2 = (const float*)d_in[10];
  const float* proj_b2 = (const float*)d_in[11];
  const int* start_idx = (const int*)d_in[12];
  float* out = (float*)d_out;  // reference output dtype is float32

  char* ws = (char*)d_ws;
  size_t off = 0;
  auto alloc = [&](size_t bytes) -> void* {
    void* p = ws + off;
    off += (bytes + 255) & ~(size_t)255;
    return p;
  };
  _Float16* Wih = (_Float16*)alloc((size_t)NL * NG * NH * 2);
  _Float16* Whh = (_Float16*)alloc((size_t)NL * NG * NH * 2);
  float* bias = (float*)alloc((size_t)NL * NG * 4);
  _Float16* hx = (_Float16*)alloc((size_t)2 * NB * NH * 2);   // chain-output double buffer
  _Float16* h0b = (_Float16*)alloc((size_t)NB * NH * 2);
  _Float16* x0 = (_Float16*)alloc((size_t)NB * NH * 2);
  _Float16* outsb = (_Float16*)alloc((size_t)NT * NB * NH * 2);
  float* feat1 = (float*)alloc((size_t)NB * NH * 4);
  _Float16* pw1 = (_Float16*)alloc((size_t)2 * NH * NH * 2);
  _Float16* pw2 = (_Float16*)alloc((size_t)NVP * NK * 2);
  float* pb1 = (float*)alloc((size_t)2 * NH * 4);
  float* pb2 = (float*)alloc((size_t)NVP * 4);
  int* flags = (int*)alloc(256 * 16 * 4);
  int* rowmap = (int*)alloc(256 * 4);
  int* colmap = (int*)alloc(256 * 4);
  if (off > ws_size) return;  // insufficient workspace — fail visibly

  k_probe<<<dim3(1), dim3(64), 0, stream>>>(rowmap, colmap);
  k_prep_w<<<dim3(2048), dim3(256), 0, stream>>>(w_ih, w_hh, b_ih, b_hh, Wih, Whh, bias);
  k_prep_misc<<<dim3(1024), dim3(256), 0, stream>>>(embed, start_idx, proj_w1, proj_b1, proj_w2, proj_b2,
                                                    x0, pw1, pb1, pw2, pb2, flags);
  k_gemv512<<<dim3(NB), dim3(256), 0, stream>>>(feat, visual_w, visual_b, feat1);
  k_gemv2_h0<<<dim3(NB), dim3(256), 0, stream>>>(feat1, visual_w, visual_b, h0b);
  k_lstm<<<dim3(256), dim3(512), 0, stream>>>(Wih, Whh, bias, hx, h0b, x0, outsb, rowmap, colmap, flags);
  k_proj<<<dim3(3200), dim3(256), 0, stream>>>(outsb, pw1, pb1, pw2, pb2, rowmap, colmap, out);
}

// Round 15
// 4578.104 us; speedup vs baseline: 1.8889x; 1.8889x over previous
//
#include <hip/hip_runtime.h>
#include <hip/hip_bf16.h>
#include <hip/hip_fp16.h>

// Problem constants
#define NB 256   // batch
#define NH 512   // hidden
#define NL 3     // lstm layers
#define NT 200   // time steps
#define NV 100   // vocab
#define NVP 112  // vocab padded to 7*16
#define NG 2048  // 4*NH gate rows per layer (permuted r = hu*4+g)
#define NK 1024  // 2*NH (proj2 K)
#define NS (NT * NL)  // 600 chain cells; s = 3t+l; input(s) = output(s-1)

using f16x8 = __attribute__((ext_vector_type(8))) _Float16;
using f32x4 = __attribute__((ext_vector_type(4))) float;
using u32x4 = __attribute__((ext_vector_type(4))) unsigned int;

__device__ __forceinline__ float sigf(float x) { return 1.f / (1.f + __expf(-x)); }
__device__ __forceinline__ float tanhf_(float x) { return 2.f / (1.f + __expf(-2.f * x)) - 1.f; }

// ---------------- fused setup: MFMA probe + weight permute + misc prep + flag reset ----------------
__global__ void k_setup(const float* __restrict__ w_ih, const float* __restrict__ w_hh,
                        const float* __restrict__ b_ih, const float* __restrict__ b_hh,
                        const float* __restrict__ embed, const int* __restrict__ start_idx,
                        const float* __restrict__ w1, const float* __restrict__ b1,
                        const float* __restrict__ w2, const float* __restrict__ b2,
                        _Float16* __restrict__ Wih, _Float16* __restrict__ Whh,
                        float* __restrict__ bias, _Float16* __restrict__ x0,
                        _Float16* __restrict__ pw1, float* __restrict__ pb1,
                        _Float16* __restrict__ pw2, float* __restrict__ pb2,
                        int* __restrict__ flags, int* __restrict__ rowmap, int* __restrict__ colmap) {
  const int stride = gridDim.x * blockDim.x;
  const int tid0 = blockIdx.x * blockDim.x + threadIdx.x;
  // --- probe (block 0, one wave) ---
  if (blockIdx.x == 0 && threadIdx.x < 64) {
    const int lane = threadIdx.x & 63;
    f16x8 a, b;
    const _Float16 idv = (_Float16)(float)(lane & 15);
    const _Float16 inv = (_Float16)(1.f / 32.f);
#pragma unroll
    for (int j = 0; j < 8; ++j) { a[j] = idv; b[j] = inv; }
    f32x4 d = {0.f, 0.f, 0.f, 0.f};
    d = __builtin_amdgcn_mfma_f32_16x16x32_f16(a, b, d, 0, 0, 0);
#pragma unroll
    for (int r = 0; r < 4; ++r) rowmap[lane * 4 + r] = (int)(d[r] + 0.5f);
#pragma unroll
    for (int j = 0; j < 8; ++j) { a[j] = inv; b[j] = idv; }
    f32x4 e = {0.f, 0.f, 0.f, 0.f};
    e = __builtin_amdgcn_mfma_f32_16x16x32_f16(a, b, e, 0, 0, 0);
#pragma unroll
    for (int r = 0; r < 4; ++r) colmap[lane * 4 + r] = (int)(e[r] + 0.5f);
  }
  // --- weight split+permute to fp16 ---
  for (int idx = tid0; idx < NL * NG * NH; idx += stride) {
    const int k = idx & (NH - 1);
    const int r = (idx >> 9) & (NG - 1);
    const int l = idx >> 20;
    const int hu = r >> 2, g = r & 3;
    const size_t soff = ((size_t)(l * NG + g * NH + hu)) * NH + k;
    Wih[idx] = (_Float16)w_ih[soff];
    Whh[idx] = (_Float16)w_hh[soff];
  }
  for (int idx = tid0; idx < NL * NG; idx += stride) {
    const int r = idx & (NG - 1);
    const int l = idx >> 11;
    const int hu = r >> 2, g = r & 3;
    const int srow = l * NG + g * NH + hu;
    bias[idx] = b_ih[srow] + b_hh[srow];
  }
  // --- misc prep ---
  for (int i = tid0; i < 256 * 16; i += stride) flags[i] = 0;
  const int st = start_idx[0];
  for (int i = tid0; i < NB * NH; i += stride)
    x0[i] = (_Float16)embed[(size_t)st * NH + (i & (NH - 1))];
  for (int i = tid0; i < 2 * NH * NH; i += stride)
    pw1[i] = (_Float16)w1[i];
  for (int i = tid0; i < NVP * NK; i += stride) {
    const int r = i >> 10;
    pw2[i] = (_Float16)((r < NV) ? w2[i] : 0.f);
  }
  for (int i = tid0; i < 2 * NH; i += stride) pb1[i] = b1[i];
  for (int i = tid0; i < NVP; i += stride) pb2[i] = (i < NV) ? b2[i] : 0.f;
}

// ---------------- visual GEMV ----------------
__global__ void k_gemv512(const float* __restrict__ x, const float* __restrict__ w,
                          const float* __restrict__ bias, float* __restrict__ out) {
  const int b = blockIdx.x;
  __shared__ float xs[NH];
  for (int i = threadIdx.x; i < NH; i += 256) xs[i] = x[(size_t)b * NH + i];
  __syncthreads();
  const int wave = threadIdx.x >> 6, lane = threadIdx.x & 63;
  for (int j = wave; j < NH; j += 4) {
    const float* wr = w + (size_t)j * NH;
    float s = 0.f;
#pragma unroll
    for (int i = 0; i < 8; ++i) s += wr[lane + i * 64] * xs[lane + i * 64];
#pragma unroll
    for (int o = 32; o > 0; o >>= 1) s += __shfl_down(s, o);
    if (lane == 0) out[(size_t)b * NH + j] = s + bias[j];
  }
}

// second visual GEMV -> h0 (fp16)
__global__ void k_gemv2_h0(const float* __restrict__ feat1, const float* __restrict__ w,
                           const float* __restrict__ bias, _Float16* __restrict__ h0b) {
  const int b = blockIdx.x;
  __shared__ float xs[NH];
  for (int i = threadIdx.x; i < NH; i += 256) xs[i] = feat1[(size_t)b * NH + i];
  __syncthreads();
  const int wave = threadIdx.x >> 6, lane = threadIdx.x & 63;
  for (int j = wave; j < NH; j += 4) {
    const float* wr = w + (size_t)j * NH;
    float s = 0.f;
#pragma unroll
    for (int i = 0; i < 8; ++i) s += wr[lane + i * 64] * xs[lane + i * 64];
#pragma unroll
    for (int o = 32; o > 0; o >>= 1) s += __shfl_down(s, o);
    if (lane == 0) h0b[(size_t)b * NH + j] = (_Float16)(s + bias[j]);
  }
}

// ---------------- persistent LSTM chain (r12-proven): reg-cached A, gap-filled h-GEMM ----------------
// 256 blocks x 512 threads. bm=bid>>5 (8 groups x 32 blocks; group = 32-row batch slice),
// bn=(jj&7)*4+(jj>>3) (XCD-local W -> L2-resident). 8 waves = 4 gate-slices x 2 K-halves.
__global__ __launch_bounds__(512, 2) void k_lstm(const _Float16* __restrict__ Wih,
                                                 const _Float16* __restrict__ Whh,
                                                 const float* __restrict__ bias,
                                                 _Float16* hx, const _Float16* __restrict__ h0b,
                                                 const _Float16* __restrict__ x0,
                                                 _Float16* __restrict__ outs,
                                                 const int* __restrict__ rowmap,
                                                 const int* __restrict__ colmap,
                                                 int* flags) {
  const int tid = threadIdx.x;
  const int lane = tid & 63;
  const int wave = tid >> 6;
  const int bid = blockIdx.x;
  const int jj = bid & 31;
  const int bm = bid >> 5;
  const int bn = (jj & 7) * 4 + (jj >> 3);
  const int gbase = bm * 32;
  const int wn = wave & 3;    // gate 16-slice
  const int kh = wave >> 2;   // K half (0: k<256, 1: k>=256)
  const int lr = lane & 15;
  const int lh = lane >> 4;
  const int nb0 = bn * 64 + wn * 16;
  __shared__ _Float16 Als[32][512];     // XOR-swizzled: chunk c at (c ^ (row&7))
  __shared__ float gl[2][32][68];       // x-partials per K-half
  __shared__ float pend[3][2][32][68];  // pending h-partials ring
  __shared__ _Float16 hout[32][16];

  int rm[4], cm[4];
#pragma unroll
  for (int r = 0; r < 4; ++r) {
    rm[r] = rowmap[lane * 4 + r];
    cm[r] = colmap[lane * 4 + r];
  }
  const int bl_ = tid >> 4;   // cell ownership: batch row 0..31
  const int hu = tid & 15;    // hidden unit 0..15
  float creg[NL] = {0.f, 0.f, 0.f};
  float bsv[NL][4];
#pragma unroll
  for (int l = 0; l < NL; ++l)
#pragma unroll
    for (int g = 0; g < 4; ++g) bsv[l][g] = bias[l * NG + (bn * 16 + hu) * 4 + g];

  f16x8 wx[8], wh[8], areg[16];

#define PREFETCH(LX, LZ)                                                          \
  do {                                                                            \
    const _Float16* wbx = Wih + ((size_t)((LX) * NG + nb0 + lr)) * NH + kh * 256 + lh * 8; \
    const _Float16* wbh = Whh + ((size_t)((LZ) * NG + nb0 + lr)) * NH + kh * 256 + lh * 8; \
    _Pragma("unroll") for (int k_ = 0; k_ < 8; ++k_) {                            \
      wx[k_] = *(const f16x8*)(wbx + k_ * 32);                                    \
      wh[k_] = *(const f16x8*)(wbh + k_ * 32);                                    \
    }                                                                             \
  } while (0)

#define LOAD_AREG()                                                               \
  do {                                                                            \
    _Pragma("unroll") for (int kk = 0; kk < 8; ++kk) {                            \
      const int c_ = kh * 32 + kk * 4 + lh;                                       \
      areg[kk] = *(const f16x8*)&Als[lr][(c_ ^ (lr & 7)) * 8];                    \
      areg[8 + kk] = *(const f16x8*)&Als[16 + lr][(c_ ^ (lr & 7)) * 8];           \
    }                                                                             \
  } while (0)

#define STAGE_A(SRC, VOLQ)                                                        \
  do {                                                                            \
    _Pragma("unroll") for (int c = 0; c < 4; ++c) {                               \
      const int i_ = tid + c * 512;                                               \
      const int rr = i_ >> 6, cc = i_ & 63;                                       \
      u32x4 v_ = *(const VOLQ u32x4*)((SRC) + (size_t)(bm * 32 + rr) * NH + cc * 8); \
      *(u32x4*)&Als[rr][(cc ^ (rr & 7)) * 8] = v_;                                \
    }                                                                             \
  } while (0)

  // ---- prologue: pend[lp][kh] = (h0 @ Whh[lp]^T) partials for the t=0 cells ----
  STAGE_A(h0b, );
  __syncthreads();
  LOAD_AREG();
#pragma unroll 1
  for (int lp = 0; lp < 3; ++lp) {
    const _Float16* wbh = Whh + ((size_t)(lp * NG + nb0 + lr)) * NH + kh * 256 + lh * 8;
    f16x8 wt[8];
#pragma unroll
    for (int k_ = 0; k_ < 8; ++k_) wt[k_] = *(const f16x8*)(wbh + k_ * 32);
    f32x4 a0 = {0.f, 0.f, 0.f, 0.f}, a1 = {0.f, 0.f, 0.f, 0.f};
#pragma unroll
    for (int kk = 0; kk < 8; ++kk) {
      a0 = __builtin_amdgcn_mfma_f32_16x16x32_f16(areg[kk], wt[kk], a0, 0, 0, 0);
      a1 = __builtin_amdgcn_mfma_f32_16x16x32_f16(areg[8 + kk], wt[kk], a1, 0, 0, 0);
    }
#pragma unroll
    for (int r = 0; r < 4; ++r) {
      pend[lp][kh][rm[r]][wn * 16 + cm[r]] = a0[r];
      pend[lp][kh][16 + rm[r]][wn * 16 + cm[r]] = a1[r];
    }
  }
  PREFETCH(0, 2);  // x: Wih[0] for s=0 (h slot unused at s=0)
  __syncthreads();
  STAGE_A(x0, );   // A for s=0
  __syncthreads();

  // ---- main chain ----
#pragma unroll 1
  for (int t = 0; t < NT; ++t) {
#pragma unroll
    for (int l = 0; l < NL; ++l) {
      const int s = t * 3 + l;
      // phase A: x-GEMM, caching A fragments in registers
      LOAD_AREG();
      {
        f32x4 a0 = {0.f, 0.f, 0.f, 0.f}, a1 = {0.f, 0.f, 0.f, 0.f};
#pragma unroll
        for (int kk = 0; kk < 8; ++kk) {
          a0 = __builtin_amdgcn_mfma_f32_16x16x32_f16(areg[kk], wx[kk], a0, 0, 0, 0);
          a1 = __builtin_amdgcn_mfma_f32_16x16x32_f16(areg[8 + kk], wx[kk], a1, 0, 0, 0);
        }
#pragma unroll
        for (int r = 0; r < 4; ++r) {
          gl[kh][rm[r]][wn * 16 + cm[r]] = a0[r];
          gl[kh][16 + rm[r]][wn * 16 + cm[r]] = a1[r];
        }
      }
      __syncthreads();
      // cell update
      {
        const f32x4 gx0 = *(const f32x4*)&gl[0][bl_][hu * 4];
        const f32x4 gx1 = *(const f32x4*)&gl[1][bl_][hu * 4];
        const f32x4 gh0 = *(const f32x4*)&pend[l][0][bl_][hu * 4];
        const f32x4 gh1 = *(const f32x4*)&pend[l][1][bl_][hu * 4];
        const float gi = gx0[0] + gx1[0] + gh0[0] + gh1[0] + bsv[l][0];
        const float gf = gx0[1] + gx1[1] + gh0[1] + gh1[1] + bsv[l][1];
        const float gg = gx0[2] + gx1[2] + gh0[2] + gh1[2] + bsv[l][2];
        const float go = gx0[3] + gx1[3] + gh0[3] + gh1[3] + bsv[l][3];
        const float cn = sigf(gf) * creg[l] + sigf(gi) * tanhf_(gg);
        const float hn = sigf(go) * tanhf_(cn);
        creg[l] = cn;
        hout[bl_][hu] = (_Float16)hn;
      }
      __syncthreads();
      // phase B: publish + register-only h-GEMM (drain hidden) + poll + stage
      if (wave == 0) {
        const int row = lane >> 1, half = lane & 1;
        _Float16* dst = hx + (size_t)(s & 1) * NB * NH + (size_t)(bm * 32 + row) * NH + bn * 16 + half * 8;
        u32x4 v = *(const u32x4*)&hout[row][half * 8];
        *(volatile u32x4*)dst = v;
      }
      if (s >= 1 && s <= NS - 3) {
        const int l2 = (l + 2) % 3;
        f32x4 a0 = {0.f, 0.f, 0.f, 0.f}, a1 = {0.f, 0.f, 0.f, 0.f};
#pragma unroll
        for (int kk = 0; kk < 8; ++kk) {
          a0 = __builtin_amdgcn_mfma_f32_16x16x32_f16(areg[kk], wh[kk], a0, 0, 0, 0);
          a1 = __builtin_amdgcn_mfma_f32_16x16x32_f16(areg[8 + kk], wh[kk], a1, 0, 0, 0);
        }
#pragma unroll
        for (int r = 0; r < 4; ++r) {
          pend[l2][kh][rm[r]][wn * 16 + cm[r]] = a0[r];
          pend[l2][kh][16 + rm[r]][wn * 16 + cm[r]] = a1[r];
        }
      }
      if (wave == 0) {
        asm volatile("s_waitcnt vmcnt(0)" ::: "memory");
        if (lane == 0) *(volatile int*)&flags[(gbase + jj) * 16] = s + 1;
      }
      if (wave == 1 && l == 2) {
        const int row = lane >> 1, half = lane & 1;
        _Float16* dst = outs + ((size_t)t * NB + bm * 32 + row) * NH + bn * 16 + half * 8;
        *(u32x4*)dst = *(const u32x4*)&hout[row][half * 8];
      }
      if (s < NS - 1) {
        PREFETCH((l + 1) % 3, l);  // W for stage s+1: Wih[l+1], Whh[l2(s+1)=l]
        if (lane < 32) {
          const volatile int* fp = (const volatile int*)&flags[(gbase + lane) * 16];
          while (*fp < s + 1) __builtin_amdgcn_s_sleep(1);
        }
        STAGE_A(hx + (size_t)(s & 1) * NB * NH, volatile);
        __syncthreads();
      }
    }
  }
#undef STAGE_A
#undef LOAD_AREG
#undef PREFETCH
}

// ---------------- projection head: 32 rows/block (halved pw1 re-reads) ----------------
// grid 1600; 4 waves: (wave>>1) = M 16-tile, (wave&1) = N 512-half. hm[32][1032] LDS.
__global__ __launch_bounds__(256) void k_proj(const _Float16* __restrict__ outs, const _Float16* __restrict__ pw1,
                                              const float* __restrict__ pb1, const _Float16* __restrict__ pw2,
                                              const float* __restrict__ pb2,
                                              const int* __restrict__ rowmap, const int* __restrict__ colmap,
                                              float* __restrict__ out) {
  const int tid = threadIdx.x;
  const int lane = tid & 63;
  const int wave = tid >> 6;
  const int lr = lane & 15;
  const int lh = lane >> 4;
  const int mbase = blockIdx.x * 32;
  const int mt_w = wave >> 1;
  const int nh_w = wave & 1;
  __shared__ _Float16 hm[32][NK + 8];
  int rm[4], cm[4];
#pragma unroll
  for (int r = 0; r < 4; ++r) {
    rm[r] = rowmap[lane * 4 + r];
    cm[r] = colmap[lane * 4 + r];
  }
  const int mrow = mbase + mt_w * 16 + lr;
  const _Float16* ap = outs + ((size_t)(mrow % NT) * NB + (mrow / NT)) * NH + lh * 8;
  f16x8 areg[16];
#pragma unroll
  for (int kk = 0; kk < 16; ++kk) areg[kk] = *(const f16x8*)(ap + kk * 32);
  // phase 1: hmid[32][1024]
#pragma unroll 1
  for (int nf = 0; nf < 32; ++nf) {
    const int n0 = nh_w * 512 + nf * 16;
    const _Float16* bp = pw1 + (size_t)(n0 + lr) * NH + lh * 8;
    f32x4 aA = {0.f, 0.f, 0.f, 0.f}, aB = {0.f, 0.f, 0.f, 0.f};
#pragma unroll
    for (int kk = 0; kk < 8; ++kk) {
      aA = __builtin_amdgcn_mfma_f32_16x16x32_f16(areg[kk], *(const f16x8*)(bp + kk * 32), aA, 0, 0, 0);
      aB = __builtin_amdgcn_mfma_f32_16x16x32_f16(areg[8 + kk], *(const f16x8*)(bp + (8 + kk) * 32), aB, 0, 0, 0);
    }
#pragma unroll
    for (int r = 0; r < 4; ++r) {
      const float v = aA[r] + aB[r] + pb1[n0 + cm[r]];
      const float gv = 0.5f * v * (1.f + erff(v * 0.70710678118654752f));
      hm[mt_w * 16 + rm[r]][n0 + cm[r]] = (_Float16)gv;
    }
  }
  __syncthreads();
  // phase 2: logits[32][112], K=1024 from LDS; 14 units = 2 M-tiles x 7 N-tiles
  for (int unit = wave; unit < 14; unit += 4) {
    const int mt = unit / 7, nf = unit % 7;
    const int n0 = nf * 16;
    f32x4 acc = {0.f, 0.f, 0.f, 0.f};
    const _Float16* bp = pw2 + (size_t)(n0 + lr) * NK + lh * 8;
#pragma unroll 4
    for (int kk = 0; kk < 32; ++kk) {
      f16x8 a = *(const f16x8*)(&hm[mt * 16 + lr][kk * 32 + lh * 8]);
      f16x8 b = *(const f16x8*)(bp + kk * 32);
      acc = __builtin_amdgcn_mfma_f32_16x16x32_f16(a, b, acc, 0, 0, 0);
    }
#pragma unroll
    for (int r = 0; r < 4; ++r) {
      const int v = n0 + cm[r];
      if (v < NV) {
        const int m = mbase + mt * 16 + rm[r];
        out[((size_t)(m / NT) * NV + v) * NT + (m % NT)] = acc[r] + pb2[v];
      }
    }
  }
}

extern "C" void kernel_launch(void* const* d_in, const int* in_sizes, int n_in,
                              void* d_out, int out_size, void* d_ws, size_t ws_size,
                              hipStream_t stream) {
  const float* feat = (const float*)d_in[0];
  const float* visual_w = (const float*)d_in[1];
  const float* visual_b = (const float*)d_in[2];
  const float* embed = (const float*)d_in[3];
  const float* w_ih = (const float*)d_in[4];
  const float* w_hh = (const float*)d_in[5];
  const float* b_ih = (const float*)d_in[6];
  const float* b_hh = (const float*)d_in[7];
  const float* proj_w1 = (const float*)d_in[8];
  const float* proj_b1 = (const float*)d_in[9];
  const float* proj_w2 = (const float*)d_in[10];
  const float* proj_b2 = (const float*)d_in[11];
  const int* start_idx = (const int*)d_in[12];
  float* out = (float*)d_out;  // reference output dtype is float32

  char* ws = (char*)d_ws;
  size_t off = 0;
  auto alloc = [&](size_t bytes) -> void* {
    void* p = ws + off;
    off += (bytes + 255) & ~(size_t)255;
    return p;
  };
  _Float16* Wih = (_Float16*)alloc((size_t)NL * NG * NH * 2);
  _Float16* Whh = (_Float16*)alloc((size_t)NL * NG * NH * 2);
  float* bias = (float*)alloc((size_t)NL * NG * 4);
  _Float16* hx = (_Float16*)alloc((size_t)2 * NB * NH * 2);   // chain-output double buffer
  _Float16* h0b = (_Float16*)alloc((size_t)NB * NH * 2);
  _Float16* x0 = (_Float16*)alloc((size_t)NB * NH * 2);
  _Float16* outsb = (_Float16*)alloc((size_t)NT * NB * NH * 2);
  float* feat1 = (float*)alloc((size_t)NB * NH * 4);
  _Float16* pw1 = (_Float16*)alloc((size_t)2 * NH * NH * 2);
  _Float16* pw2 = (_Float16*)alloc((size_t)NVP * NK * 2);
  float* pb1 = (float*)alloc((size_t)2 * NH * 4);
  float* pb2 = (float*)alloc((size_t)NVP * 4);
  int* flags = (int*)alloc(256 * 16 * 4);
  int* rowmap = (int*)alloc(256 * 4);
  int* colmap = (int*)alloc(256 * 4);
  if (off > ws_size) return;  // insufficient workspace — fail visibly

  k_setup<<<dim3(2048), dim3(256), 0, stream>>>(w_ih, w_hh, b_ih, b_hh, embed, start_idx,
                                                proj_w1, proj_b1, proj_w2, proj_b2,
                                                Wih, Whh, bias, x0, pw1, pb1, pw2, pb2,
                                                flags, rowmap, colmap);
  k_gemv512<<<dim3(NB), dim3(256), 0, stream>>>(feat, visual_w, visual_b, feat1);
  k_gemv2_h0<<<dim3(NB), dim3(256), 0, stream>>>(feat1, visual_w, visual_b, h0b);
  k_lstm<<<dim3(256), dim3(512), 0, stream>>>(Wih, Whh, bias, hx, h0b, x0, outsb, rowmap, colmap, flags);
  k_proj<<<dim3(1600), dim3(256), 0, stream>>>(outsb, pw1, pb1, pw2, pb2, rowmap, colmap, out);
}